// Round 1
// baseline (513.222 us; speedup 1.0000x reference)
//
#include <hip/hip_runtime.h>
#include <math.h>

#define N_NODES 50000
#define N_EDGES 600000
#define D 128
#define TWO_D 256
#define EPS_MSG 1e-7f
#define BN_EPS 1e-5f
#define LN_EPS 1e-5f
#define R1 16
#define R2 16
#define BN_ROWS 128

// ---------------- CSR build ----------------

__global__ void count_kernel(const int* __restrict__ dst, int* __restrict__ counts) {
    int i = blockIdx.x * blockDim.x + threadIdx.x;
    if (i < N_EDGES) atomicAdd(&counts[dst[i]], 1);
}

// single-block chunked Hillis-Steele inclusive scan -> exclusive offsets[N+1]
__global__ void scan_kernel(const int* __restrict__ counts, int* __restrict__ offsets) {
    __shared__ int buf[1024];
    __shared__ int carry;
    if (threadIdx.x == 0) { carry = 0; offsets[0] = 0; }
    __syncthreads();
    for (int base = 0; base < N_NODES; base += 1024) {
        int i = base + threadIdx.x;
        int v = (i < N_NODES) ? counts[i] : 0;
        buf[threadIdx.x] = v;
        __syncthreads();
        for (int off = 1; off < 1024; off <<= 1) {
            int t = (threadIdx.x >= off) ? buf[threadIdx.x - off] : 0;
            __syncthreads();
            buf[threadIdx.x] += t;
            __syncthreads();
        }
        int incl = buf[threadIdx.x] + carry;
        if (i < N_NODES) offsets[i + 1] = incl;
        __syncthreads();
        if (threadIdx.x == 1023) carry = incl;
        __syncthreads();
    }
}

__global__ void scatter_kernel(const int* __restrict__ src, const int* __restrict__ dst,
                               const int* __restrict__ offsets, int* __restrict__ cursor,
                               int* __restrict__ csr_src) {
    int i = blockIdx.x * blockDim.x + threadIdx.x;
    if (i < N_EDGES) {
        int d = dst[i];
        int pos = offsets[d] + atomicAdd(&cursor[d], 1);
        csr_src[pos] = src[i];
    }
}

// ---------------- softmax aggregation (one block per node, thread per channel) ----------------
// agg = sum(msg*e)/(sum(e)+1e-16); softmax is shift-invariant, logits bounded -> no max pass.
__global__ __launch_bounds__(D) void agg_kernel(const float* __restrict__ x,
                                                const int* __restrict__ offsets,
                                                const int* __restrict__ csr_src,
                                                const float* __restrict__ t_ptr,
                                                float* __restrict__ h0) {
    int n = blockIdx.x;
    int c = threadIdx.x;
    int beg = offsets[n], end = offsets[n + 1];
    float tv = t_ptr[0];
    float s = 0.f, num = 0.f;
    for (int j = beg; j < end; ++j) {
        int src = csr_src[j];                     // uniform across block -> scalar load
        float v = x[src * D + c];                 // coalesced 512B row gather
        float msg = fmaxf(v, 0.f) + EPS_MSG;
        float p = __expf(msg * tv);
        s += p;
        num += p * msg;
    }
    float agg = num / (s + 1e-16f);
    h0[n * D + c] = agg + x[n * D + c];           // residual fused here
}

// ---------------- GEMM1: h1[N,256] = h0[N,128] @ W1 + b1 ----------------
__global__ __launch_bounds__(256) void gemm1_kernel(const float* __restrict__ h0,
                                                    const float* __restrict__ W1,
                                                    const float* __restrict__ b1,
                                                    float* __restrict__ h1) {
    __shared__ float As[D][R1 + 4];               // [k][r], padded (8-way instead of 32-way store conflict)
    int row0 = blockIdx.x * R1;                   // N divisible by 16
    for (int i = threadIdx.x; i < R1 * D; i += 256) {
        int r = i >> 7, k = i & (D - 1);
        As[k][r] = h0[(row0 + r) * D + k];        // coalesced global read
    }
    __syncthreads();
    int c = threadIdx.x;                          // output column 0..255
    float acc[R1];
#pragma unroll
    for (int r = 0; r < R1; ++r) acc[r] = 0.f;
    for (int k = 0; k < D; ++k) {
        float w = W1[k * TWO_D + c];              // coalesced, L2-resident
#pragma unroll
        for (int q = 0; q < 4; ++q) {
            float4 a = ((const float4*)&As[k][0])[q];  // broadcast b128 reads
            acc[4 * q + 0] += a.x * w;
            acc[4 * q + 1] += a.y * w;
            acc[4 * q + 2] += a.z * w;
            acc[4 * q + 3] += a.w * w;
        }
    }
    float bias = b1[c];
#pragma unroll
    for (int r = 0; r < R1; ++r) h1[(row0 + r) * TWO_D + c] = acc[r] + bias;
}

// ---------------- BatchNorm stats over N (column sums) ----------------
__global__ __launch_bounds__(TWO_D) void bn_stats_kernel(const float* __restrict__ h1,
                                                         float* __restrict__ bnacc) {
    int c = threadIdx.x;
    int row0 = blockIdx.x * BN_ROWS;
    float s = 0.f, ss = 0.f;
    for (int r = 0; r < BN_ROWS; ++r) {
        int row = row0 + r;
        if (row < N_NODES) {
            float v = h1[row * TWO_D + c];
            s += v;
            ss += v * v;
        }
    }
    atomicAdd(&bnacc[c], s);
    atomicAdd(&bnacc[TWO_D + c], ss);
}

__global__ __launch_bounds__(TWO_D) void bn_finalize_kernel(const float* __restrict__ bnacc,
                                                            const float* __restrict__ g,
                                                            const float* __restrict__ b,
                                                            float* __restrict__ scaleshift) {
    int c = threadIdx.x;
    float mean = bnacc[c] * (1.f / N_NODES);
    float var = bnacc[TWO_D + c] * (1.f / N_NODES) - mean * mean;
    float sc = g[c] * rsqrtf(var + BN_EPS);
    scaleshift[c] = sc;
    scaleshift[TWO_D + c] = b[c] - mean * sc;
}

// ---------------- GEMM2 + LayerNorm + activation mix + residual ----------------
// reads h1, applies BN affine + relu on load; block computes 16 full rows of y
// so LayerNorm is done in-block.
__global__ __launch_bounds__(D) void gemm2_kernel(const float* __restrict__ h1,
                                                  const float* __restrict__ scaleshift,
                                                  const float* __restrict__ W2,
                                                  const float* __restrict__ b2,
                                                  const float* __restrict__ ln_g,
                                                  const float* __restrict__ ln_b,
                                                  const float* __restrict__ x,
                                                  float* __restrict__ out) {
    __shared__ float As[TWO_D][R2 + 4];           // [k][r]
    __shared__ float yt[R2][D + 4];
    __shared__ float mu_s[R2], rstd_s[R2];
    int row0 = blockIdx.x * R2;                   // N divisible by 16
    for (int i = threadIdx.x; i < R2 * TWO_D; i += D) {
        int r = i >> 8, k = i & (TWO_D - 1);
        float v = h1[(row0 + r) * TWO_D + k];
        v = fmaxf(v * scaleshift[k] + scaleshift[TWO_D + k], 0.f);  // BN + ReLU fused
        As[k][r] = v;
    }
    __syncthreads();
    int c = threadIdx.x;                          // output column 0..127
    float acc[R2];
#pragma unroll
    for (int r = 0; r < R2; ++r) acc[r] = 0.f;
    for (int k = 0; k < TWO_D; ++k) {
        float w = W2[k * D + c];
#pragma unroll
        for (int q = 0; q < 4; ++q) {
            float4 a = ((const float4*)&As[k][0])[q];
            acc[4 * q + 0] += a.x * w;
            acc[4 * q + 1] += a.y * w;
            acc[4 * q + 2] += a.z * w;
            acc[4 * q + 3] += a.w * w;
        }
    }
    float bias = b2[c];
#pragma unroll
    for (int r = 0; r < R2; ++r) yt[r][c] = acc[r] + bias;
    __syncthreads();
    // LayerNorm stats: 8 threads per row
    {
        int r = threadIdx.x >> 3;
        int lane8 = threadIdx.x & 7;
        float s = 0.f, ss = 0.f;
        for (int j = lane8; j < D; j += 8) {
            float v = yt[r][j];
            s += v;
            ss += v * v;
        }
#pragma unroll
        for (int o = 1; o < 8; o <<= 1) {
            s += __shfl_xor(s, o);
            ss += __shfl_xor(ss, o);
        }
        if (lane8 == 0) {
            float mu = s * (1.f / D);
            float var = ss * (1.f / D) - mu * mu;
            mu_s[r] = mu;
            rstd_s[r] = rsqrtf(var + LN_EPS);
        }
    }
    __syncthreads();
    float lg = ln_g[c], lb = ln_b[c];
#pragma unroll
    for (int rr = 0; rr < R2; ++rr) {
        float y = yt[rr][c];
        float z = (y - mu_s[rr]) * rstd_s[rr] * lg + lb;
        float tilde = 0.5f * fmaxf(z, 0.f) + 0.5f * z;   // (C-beta)*relu(z)+beta*z
        int row = row0 + rr;
        out[row * D + c] = 0.5f * x[row * D + c] + tilde; // (C-beta)*x + tilde
    }
}

// ---------------- launch ----------------

extern "C" void kernel_launch(void* const* d_in, const int* in_sizes, int n_in,
                              void* d_out, int out_size, void* d_ws, size_t ws_size,
                              hipStream_t stream) {
    const float* x    = (const float*)d_in[0];
    const int*   ei   = (const int*)d_in[1];
    const float* t    = (const float*)d_in[2];
    const float* W1   = (const float*)d_in[3];
    const float* b1   = (const float*)d_in[4];
    const float* bn_g = (const float*)d_in[5];
    const float* bn_b = (const float*)d_in[6];
    const float* W2   = (const float*)d_in[7];
    const float* b2   = (const float*)d_in[8];
    const float* ln_g = (const float*)d_in[9];
    const float* ln_b = (const float*)d_in[10];
    float* out = (float*)d_out;

    char* ws = (char*)d_ws;
    size_t off = 0;
    auto alloc = [&](size_t bytes) -> void* {
        void* p = ws + off;
        off = (off + bytes + 255) & ~(size_t)255;
        return p;
    };
    int*   counts     = (int*)alloc((size_t)N_NODES * 4);
    int*   offsets    = (int*)alloc((size_t)(N_NODES + 1) * 4);
    int*   csr_src    = (int*)alloc((size_t)N_EDGES * 4);
    float* h0         = (float*)alloc((size_t)N_NODES * D * 4);
    float* h1         = (float*)alloc((size_t)N_NODES * TWO_D * 4);
    float* bnacc      = (float*)alloc(2 * TWO_D * 4);
    float* scaleshift = (float*)alloc(2 * TWO_D * 4);

    const int* src = ei;
    const int* dst = ei + N_EDGES;

    hipMemsetAsync(counts, 0, (size_t)N_NODES * 4, stream);
    hipMemsetAsync(bnacc, 0, 2 * TWO_D * 4, stream);
    count_kernel<<<(N_EDGES + 255) / 256, 256, 0, stream>>>(dst, counts);
    scan_kernel<<<1, 1024, 0, stream>>>(counts, offsets);
    hipMemsetAsync(counts, 0, (size_t)N_NODES * 4, stream);
    scatter_kernel<<<(N_EDGES + 255) / 256, 256, 0, stream>>>(src, dst, offsets, counts, csr_src);
    agg_kernel<<<N_NODES, D, 0, stream>>>(x, offsets, csr_src, t, h0);
    gemm1_kernel<<<N_NODES / R1, 256, 0, stream>>>(h0, W1, b1, h1);
    bn_stats_kernel<<<(N_NODES + BN_ROWS - 1) / BN_ROWS, TWO_D, 0, stream>>>(h1, bnacc);
    bn_finalize_kernel<<<1, TWO_D, 0, stream>>>(bnacc, bn_g, bn_b, scaleshift);
    gemm2_kernel<<<N_NODES / R2, D, 0, stream>>>(h1, scaleshift, W2, b2, ln_g, ln_b, x, out);
}

// Round 2
// 356.742 us; speedup vs baseline: 1.4386x; 1.4386x over previous
//
#include <hip/hip_runtime.h>
#include <math.h>

#define N_NODES 50000
#define N_EDGES 600000
#define D 128
#define TWO_D 256
#define EPS_MSG 1e-7f
#define BN_EPS 1e-5f
#define LN_EPS 1e-5f

typedef __attribute__((ext_vector_type(8))) short short8;
typedef __attribute__((ext_vector_type(4))) float f32x4;
typedef __attribute__((ext_vector_type(4))) unsigned short ushort4v;

static __device__ __forceinline__ unsigned short f2b(float f) {
    unsigned int u = __builtin_bit_cast(unsigned int, f);
    u = u + 0x7fffu + ((u >> 16) & 1u);   // RNE (NaN not expected here)
    return (unsigned short)(u >> 16);
}
static __device__ __forceinline__ float b2f(unsigned short s) {
    unsigned int u = ((unsigned int)s) << 16;
    return __builtin_bit_cast(float, u);
}

// ---------------- weight prep: transpose + bf16 convert ----------------
// W1 [128,256] -> W1t[n][k] (n<256,k<128); W2 [256,128] -> W2t[n][k] (n<128,k<256)
__global__ __launch_bounds__(256) void prep_w(const float* __restrict__ W1,
                                              const float* __restrict__ W2,
                                              unsigned short* __restrict__ W1t,
                                              unsigned short* __restrict__ W2t) {
    int i = blockIdx.x * 256 + threadIdx.x;   // 0..65535
    if (i < 32768) {
        int n = i >> 7, k = i & 127;          // W1t[n*128+k] = W1[k*256+n]
        W1t[i] = f2b(W1[k * 256 + n]);
    } else {
        int j = i - 32768;
        int n = j >> 8, k = j & 255;          // W2t[n*256+k] = W2[k*128+n]
        W2t[j] = f2b(W2[k * 128 + n]);
    }
}

// ---------------- CSR build ----------------

__global__ void count_kernel(const int* __restrict__ dst, int* __restrict__ counts) {
    int i = blockIdx.x * blockDim.x + threadIdx.x;
    if (i < N_EDGES) atomicAdd(&counts[dst[i]], 1);
}

#define SCAN_BLOCKS 196
__global__ __launch_bounds__(256) void scan_block(const int* __restrict__ counts,
                                                  int* __restrict__ offsets,
                                                  int* __restrict__ blocksums) {
    __shared__ int buf[256];
    int tid = threadIdx.x;
    int i = blockIdx.x * 256 + tid;
    int v = (i < N_NODES) ? counts[i] : 0;
    buf[tid] = v;
    __syncthreads();
    for (int off = 1; off < 256; off <<= 1) {
        int t = (tid >= off) ? buf[tid - off] : 0;
        __syncthreads();
        buf[tid] += t;
        __syncthreads();
    }
    if (i < N_NODES) offsets[i + 1] = buf[tid];
    if (tid == 255) blocksums[blockIdx.x] = buf[255];
}

__global__ __launch_bounds__(256) void scan_sums(int* __restrict__ blocksums) {
    __shared__ int buf[256];
    int tid = threadIdx.x;
    int v = (tid < SCAN_BLOCKS) ? blocksums[tid] : 0;
    buf[tid] = v;
    __syncthreads();
    for (int off = 1; off < 256; off <<= 1) {
        int t = (tid >= off) ? buf[tid - off] : 0;
        __syncthreads();
        buf[tid] += t;
        __syncthreads();
    }
    if (tid < SCAN_BLOCKS) blocksums[tid] = buf[tid] - v;   // exclusive
}

__global__ __launch_bounds__(256) void add_base(int* __restrict__ offsets,
                                                const int* __restrict__ blocksums) {
    int i = blockIdx.x * 256 + threadIdx.x;
    if (i < N_NODES) offsets[i + 1] += blocksums[blockIdx.x];
    if (i == 0) offsets[0] = 0;
}

__global__ void scatter_kernel(const int* __restrict__ src, const int* __restrict__ dst,
                               const int* __restrict__ offsets, int* __restrict__ cursor,
                               int* __restrict__ csr_src) {
    int i = blockIdx.x * blockDim.x + threadIdx.x;
    if (i < N_EDGES) {
        int d = dst[i];
        int pos = offsets[d] + atomicAdd(&cursor[d], 1);
        csr_src[pos] = src[i];
    }
}

// ---------------- softmax aggregation; writes h0 = agg + x as bf16 ----------------
__global__ __launch_bounds__(D) void agg_kernel(const float* __restrict__ x,
                                                const int* __restrict__ offsets,
                                                const int* __restrict__ csr_src,
                                                const float* __restrict__ t_ptr,
                                                unsigned short* __restrict__ h0b) {
    int n = blockIdx.x;
    int c = threadIdx.x;
    int beg = offsets[n], end = offsets[n + 1];
    float tv = t_ptr[0];
    float s = 0.f, num = 0.f;
    for (int j = beg; j < end; ++j) {
        int src = csr_src[j];                     // uniform -> scalar load
        float v = x[src * D + c];                 // coalesced row gather
        float msg = fmaxf(v, 0.f) + EPS_MSG;
        float p = __expf(msg * tv);
        s += p;
        num += p * msg;
    }
    float agg = num / (s + 1e-16f);
    h0b[n * D + c] = f2b(agg + x[n * D + c]);     // residual fused
}

// ---------------- GEMM1 (MFMA): h1b[N,256] = bf16(h0b @ W1 + b1) ----------------
// block 256 thr = 4 waves stacked in M; wave tile 16x64 (4 col frags); K=128 -> 4 k-steps
__global__ __launch_bounds__(256) void gemm1_mfma(const unsigned short* __restrict__ h0b,
                                                  const unsigned short* __restrict__ W1t,
                                                  const float* __restrict__ b1,
                                                  unsigned short* __restrict__ h1b) {
    int tid = threadIdx.x;
    int wave = tid >> 6, lane = tid & 63;
    int quad = lane >> 4, m16 = lane & 15;
    int row0 = blockIdx.x * 64 + wave * 16;
    int col0 = blockIdx.y * 64;

    f32x4 acc[4] = {{0.f,0.f,0.f,0.f},{0.f,0.f,0.f,0.f},{0.f,0.f,0.f,0.f},{0.f,0.f,0.f,0.f}};
    int arow = row0 + m16;
    bool avalid = arow < N_NODES;
    const short8* aptr = (const short8*)(h0b + (avalid ? arow : 0) * D + quad * 8);
#pragma unroll
    for (int kk = 0; kk < 4; ++kk) {
        short8 a = aptr[kk * 4];                  // k0 = kk*32 -> 32 shorts = 4 short8
        if (!avalid) a = (short8)0;
#pragma unroll
        for (int f = 0; f < 4; ++f) {
            const short8* bptr = (const short8*)(W1t + (col0 + f * 16 + m16) * D + quad * 8);
            short8 b = bptr[kk * 4];
            acc[f] = __builtin_amdgcn_mfma_f32_16x16x32_bf16(a, b, acc[f], 0, 0, 0);
        }
    }
#pragma unroll
    for (int f = 0; f < 4; ++f) {
        int col = col0 + f * 16 + m16;
        float bias = b1[col];
#pragma unroll
        for (int r = 0; r < 4; ++r) {
            int row = row0 + quad * 4 + r;
            if (row < N_NODES) h1b[row * TWO_D + col] = f2b(acc[f][r] + bias);
        }
    }
}

// ---------------- BN stats (column sums over N) from bf16 h1 ----------------
__global__ __launch_bounds__(256) void bn_stats(const unsigned short* __restrict__ h1b,
                                                float* __restrict__ bnacc) {
    __shared__ float red[256 * 4];
    int tid = threadIdx.x;
    int cg = tid & 63, rg = tid >> 6;
    int c0 = cg * 4;
    float s[4] = {0, 0, 0, 0}, ss[4] = {0, 0, 0, 0};
    for (int row = blockIdx.x * 4 + rg; row < N_NODES; row += 256 * 4) {
        ushort4v v = *(const ushort4v*)(h1b + row * TWO_D + c0);
#pragma unroll
        for (int j = 0; j < 4; ++j) {
            float f = b2f(v[j]);
            s[j] += f;
            ss[j] += f * f;
        }
    }
#pragma unroll
    for (int j = 0; j < 4; ++j) red[tid * 4 + j] = s[j];
    __syncthreads();
    if (rg == 0) {
#pragma unroll
        for (int j = 0; j < 4; ++j) {
            float t = red[tid * 4 + j] + red[(tid + 64) * 4 + j] +
                      red[(tid + 128) * 4 + j] + red[(tid + 192) * 4 + j];
            atomicAdd(&bnacc[c0 + j], t);
        }
    }
    __syncthreads();
#pragma unroll
    for (int j = 0; j < 4; ++j) red[tid * 4 + j] = ss[j];
    __syncthreads();
    if (rg == 0) {
#pragma unroll
        for (int j = 0; j < 4; ++j) {
            float t = red[tid * 4 + j] + red[(tid + 64) * 4 + j] +
                      red[(tid + 128) * 4 + j] + red[(tid + 192) * 4 + j];
            atomicAdd(&bnacc[TWO_D + c0 + j], t);
        }
    }
}

__global__ __launch_bounds__(TWO_D) void bn_finalize_kernel(const float* __restrict__ bnacc,
                                                            const float* __restrict__ g,
                                                            const float* __restrict__ b,
                                                            float* __restrict__ scaleshift) {
    int c = threadIdx.x;
    float mean = bnacc[c] * (1.f / N_NODES);
    float var = bnacc[TWO_D + c] * (1.f / N_NODES) - mean * mean;
    float sc = g[c] * rsqrtf(var + BN_EPS);
    scaleshift[c] = sc;
    scaleshift[TWO_D + c] = b[c] - mean * sc;
}

// ---------------- GEMM2 (MFMA) + BN-affine/ReLU on load + LN + mix + residual ----------------
// block 256 thr = 4 waves side-by-side in N; wave tile 16x32 (2 col frags); K=256 -> 8 k-steps
__global__ __launch_bounds__(256) void gemm2_mfma(const unsigned short* __restrict__ h1b,
                                                  const float* __restrict__ scaleshift,
                                                  const unsigned short* __restrict__ W2t,
                                                  const float* __restrict__ b2,
                                                  const float* __restrict__ ln_g,
                                                  const float* __restrict__ ln_b,
                                                  const float* __restrict__ x,
                                                  float* __restrict__ out) {
    __shared__ float sc_s[TWO_D], sh_s[TWO_D];
    __shared__ float yt[16][D + 4];
    __shared__ float mu_s[16], rstd_s[16];
    int tid = threadIdx.x;
    sc_s[tid] = scaleshift[tid];
    sh_s[tid] = scaleshift[TWO_D + tid];
    __syncthreads();

    int wave = tid >> 6, lane = tid & 63;
    int quad = lane >> 4, m16 = lane & 15;
    int row0 = blockIdx.x * 16;                   // 50000/16 = 3125 exact

    f32x4 acc[2] = {{0.f,0.f,0.f,0.f},{0.f,0.f,0.f,0.f}};
    const unsigned short* arow = h1b + (row0 + m16) * TWO_D + quad * 8;
#pragma unroll
    for (int kk = 0; kk < 8; ++kk) {
        int kbase = kk * 32 + quad * 8;
        short8 raw = *(const short8*)(arow + kk * 32);
        short8 a;
#pragma unroll
        for (int j = 0; j < 8; ++j) {
            float v = b2f((unsigned short)raw[j]);
            v = fmaxf(v * sc_s[kbase + j] + sh_s[kbase + j], 0.f);
            a[j] = (short)f2b(v);
        }
#pragma unroll
        for (int f = 0; f < 2; ++f) {
            const short8* bptr = (const short8*)(W2t + (wave * 32 + f * 16 + m16) * TWO_D + kk * 32 + quad * 8);
            short8 b = *bptr;
            acc[f] = __builtin_amdgcn_mfma_f32_16x16x32_bf16(a, b, acc[f], 0, 0, 0);
        }
    }
#pragma unroll
    for (int f = 0; f < 2; ++f) {
        int col = wave * 32 + f * 16 + m16;
        float bias = b2[col];
#pragma unroll
        for (int r = 0; r < 4; ++r) yt[quad * 4 + r][col] = acc[f][r] + bias;
    }
    __syncthreads();
    // LN stats: 16 threads per row
    {
        int r = tid >> 4, lane16 = tid & 15;
        float s = 0.f, ss = 0.f;
        for (int j = lane16; j < D; j += 16) {
            float v = yt[r][j];
            s += v;
            ss += v * v;
        }
#pragma unroll
        for (int o = 1; o < 16; o <<= 1) {
            s += __shfl_xor(s, o);
            ss += __shfl_xor(ss, o);
        }
        if (lane16 == 0) {
            float mu = s * (1.f / D);
            float var = ss * (1.f / D) - mu * mu;
            mu_s[r] = mu;
            rstd_s[r] = rsqrtf(var + LN_EPS);
        }
    }
    __syncthreads();
    int c = tid & 127, rr = tid >> 7;
    float lg = ln_g[c], lb = ln_b[c];
#pragma unroll
    for (int rp = 0; rp < 8; ++rp) {
        int rl = rp * 2 + rr;
        int row = row0 + rl;
        float z = (yt[rl][c] - mu_s[rl]) * rstd_s[rl] * lg + lb;
        float tilde = 0.5f * fmaxf(z, 0.f) + 0.5f * z;
        out[row * D + c] = 0.5f * x[row * D + c] + tilde;
    }
}

// ---------------- launch ----------------

extern "C" void kernel_launch(void* const* d_in, const int* in_sizes, int n_in,
                              void* d_out, int out_size, void* d_ws, size_t ws_size,
                              hipStream_t stream) {
    const float* x    = (const float*)d_in[0];
    const int*   ei   = (const int*)d_in[1];
    const float* t    = (const float*)d_in[2];
    const float* W1   = (const float*)d_in[3];
    const float* b1   = (const float*)d_in[4];
    const float* bn_g = (const float*)d_in[5];
    const float* bn_b = (const float*)d_in[6];
    const float* W2   = (const float*)d_in[7];
    const float* b2   = (const float*)d_in[8];
    const float* ln_g = (const float*)d_in[9];
    const float* ln_b = (const float*)d_in[10];
    float* out = (float*)d_out;

    char* ws = (char*)d_ws;
    size_t off = 0;
    auto alloc = [&](size_t bytes) -> void* {
        void* p = ws + off;
        off = (off + bytes + 255) & ~(size_t)255;
        return p;
    };
    int*            counts     = (int*)alloc((size_t)N_NODES * 4);
    int*            offsets    = (int*)alloc((size_t)(N_NODES + 1) * 4);
    int*            blocksums  = (int*)alloc((size_t)SCAN_BLOCKS * 4);
    int*            csr_src    = (int*)alloc((size_t)N_EDGES * 4);
    unsigned short* h0b        = (unsigned short*)alloc((size_t)N_NODES * D * 2);
    unsigned short* h1b        = (unsigned short*)alloc((size_t)N_NODES * TWO_D * 2);
    unsigned short* W1t        = (unsigned short*)alloc((size_t)D * TWO_D * 2);
    unsigned short* W2t        = (unsigned short*)alloc((size_t)D * TWO_D * 2);
    float*          bnacc      = (float*)alloc(2 * TWO_D * 4);
    float*          scaleshift = (float*)alloc(2 * TWO_D * 4);

    const int* src = ei;
    const int* dst = ei + N_EDGES;

    hipMemsetAsync(counts, 0, (size_t)N_NODES * 4, stream);
    hipMemsetAsync(bnacc, 0, 2 * TWO_D * 4, stream);
    prep_w<<<256, 256, 0, stream>>>(W1, W2, W1t, W2t);
    count_kernel<<<(N_EDGES + 255) / 256, 256, 0, stream>>>(dst, counts);
    scan_block<<<SCAN_BLOCKS, 256, 0, stream>>>(counts, offsets, blocksums);
    scan_sums<<<1, 256, 0, stream>>>(blocksums);
    add_base<<<SCAN_BLOCKS, 256, 0, stream>>>(offsets, blocksums);
    hipMemsetAsync(counts, 0, (size_t)N_NODES * 4, stream);
    scatter_kernel<<<(N_EDGES + 255) / 256, 256, 0, stream>>>(src, dst, offsets, counts, csr_src);
    agg_kernel<<<N_NODES, D, 0, stream>>>(x, offsets, csr_src, t, h0b);
    {
        dim3 g((N_NODES + 63) / 64, 4);
        gemm1_mfma<<<g, 256, 0, stream>>>(h0b, W1t, b1, h1b);
    }
    bn_stats<<<256, 256, 0, stream>>>(h1b, bnacc);
    bn_finalize_kernel<<<1, TWO_D, 0, stream>>>(bnacc, bn_g, bn_b, scaleshift);
    gemm2_mfma<<<N_NODES / 16, 256, 0, stream>>>(h1b, scaleshift, W2t, b2, ln_g, ln_b, x, out);
}